// Round 3
// baseline (727.691 us; speedup 1.0000x reference)
//
#include <hip/hip_runtime.h>
#include <cstdint>

// Problem constants (fixed by reference):
#define Bc 1024
#define Tc 4096
#define Nc 2048
#define Kc 16
#define Mc 65536
#define ROW_WORDS (Mc / 32)                       // 2048 words per packed row
#define PACKED_WORDS ((size_t)Nc * ROW_WORDS)     // 4M words = 16 MiB

// ---------------- Kernel A: bit-pack memory's bit 0 ----------------
// memory is (N, M) int32; only (memory & 1) is ever consumed by the reference.
// Pack 32 consecutive ints' LSBs into one uint32 -> 16 MiB table (L3-resident).
// Each thread produces one packed word from 8 int4 loads (32 ints, 128 B).
__global__ __launch_bounds__(256) void pack_kernel(
    const int* __restrict__ memory, uint32_t* __restrict__ packed)
{
    const size_t w = (size_t)blockIdx.x * 256 + threadIdx.x;  // word index
    const int4* src = (const int4*)(memory + w * 32);
    uint32_t bw = 0;
#pragma unroll
    for (int i = 0; i < 8; ++i) {
        const int4 v = src[i];
        bw |= (uint32_t)(v.x & 1) << (i * 4);
        bw |= (uint32_t)(v.y & 1) << (i * 4 + 1);
        bw |= (uint32_t)(v.z & 1) << (i * 4 + 2);
        bw |= (uint32_t)(v.w & 1) << (i * 4 + 3);
    }
    packed[w] = bw;
}

// ---------------- Kernel B: lookup against packed table ----------------
// One block per batch row b; 256 threads; 8 n per thread.
__global__ __launch_bounds__(256) void ram_lookup_packed(
    const int* __restrict__ input_bits,        // (B, T) int32 in {0,1}
    const int* __restrict__ connections,       // (N, K) int32 in [0, T)
    const uint32_t* __restrict__ packedmem,    // (N, M/32) packed bits
    int* __restrict__ out)                     // (B, N) bool-as-int32
{
    __shared__ uint32_t bits[Tc / 32];         // 128 words = 512 B

    const int b    = blockIdx.x;
    const int tid  = threadIdx.x;
    const int lane = tid & 63;
    const int wave = tid >> 6;

    const int* row = input_bits + (size_t)b * Tc;

    // ---- Phase 1: ballot-pack input row into LDS bitset ----
#pragma unroll
    for (int i = 0; i < Tc / 256; ++i) {       // 16 iterations
        const int pos = i * 256 + wave * 64 + lane;
        const unsigned long long m = __ballot(row[pos] & 1);
        if (lane == 0) {
            const int w64 = i * 4 + wave;
            bits[w64 * 2]     = (uint32_t)m;
            bits[w64 * 2 + 1] = (uint32_t)(m >> 32);
        }
    }
    __syncthreads();

    // ---- Phase 2: build 16-bit addresses ----
    uint32_t addrs[Nc / 256];
#pragma unroll
    for (int i = 0; i < Nc / 256; ++i) {       // 8 iterations
        const int n = i * 256 + tid;
        const int4* cp = (const int4*)(connections + n * Kc);
        const int4 c0 = cp[0], c1 = cp[1], c2 = cp[2], c3 = cp[3];
        const int c[16] = {c0.x, c0.y, c0.z, c0.w,
                           c1.x, c1.y, c1.z, c1.w,
                           c2.x, c2.y, c2.z, c2.w,
                           c3.x, c3.y, c3.z, c3.w};
        uint32_t a = 0;
#pragma unroll
        for (int k = 0; k < 16; ++k) {
            const uint32_t t = (uint32_t)c[k];
            a |= ((bits[t >> 5] >> (t & 31)) & 1u) << k;
        }
        addrs[i] = a;
    }

    // ---- Phase 3: independent random bit-gathers (L2/L3-resident table) ----
    uint32_t words[Nc / 256];
#pragma unroll
    for (int i = 0; i < Nc / 256; ++i) {
        const int n = i * 256 + tid;
        words[i] = packedmem[((size_t)n << 11) + (addrs[i] >> 5)];
    }

    // ---- Phase 4: coalesced int32 stores ----
#pragma unroll
    for (int i = 0; i < Nc / 256; ++i) {
        out[(size_t)b * Nc + i * 256 + tid] = (int)((words[i] >> (addrs[i] & 31)) & 1u);
    }
}

// ---------------- Fallback: direct gather (if ws too small) ----------------
__global__ __launch_bounds__(256) void ram_lookup_direct(
    const int* __restrict__ input_bits,
    const int* __restrict__ connections,
    const int* __restrict__ memory,
    int* __restrict__ out)
{
    __shared__ uint32_t bits[Tc / 32];
    const int b = blockIdx.x, tid = threadIdx.x;
    const int lane = tid & 63, wave = tid >> 6;
    const int* row = input_bits + (size_t)b * Tc;
#pragma unroll
    for (int i = 0; i < Tc / 256; ++i) {
        const int pos = i * 256 + wave * 64 + lane;
        const unsigned long long m = __ballot(row[pos] & 1);
        if (lane == 0) {
            const int w64 = i * 4 + wave;
            bits[w64 * 2] = (uint32_t)m;
            bits[w64 * 2 + 1] = (uint32_t)(m >> 32);
        }
    }
    __syncthreads();
    uint32_t addrs[Nc / 256];
#pragma unroll
    for (int i = 0; i < Nc / 256; ++i) {
        const int n = i * 256 + tid;
        const int4* cp = (const int4*)(connections + n * Kc);
        const int4 c0 = cp[0], c1 = cp[1], c2 = cp[2], c3 = cp[3];
        const int c[16] = {c0.x, c0.y, c0.z, c0.w, c1.x, c1.y, c1.z, c1.w,
                           c2.x, c2.y, c2.z, c2.w, c3.x, c3.y, c3.z, c3.w};
        uint32_t a = 0;
#pragma unroll
        for (int k = 0; k < 16; ++k) {
            const uint32_t t = (uint32_t)c[k];
            a |= ((bits[t >> 5] >> (t & 31)) & 1u) << k;
        }
        addrs[i] = a;
    }
    int vals[Nc / 256];
#pragma unroll
    for (int i = 0; i < Nc / 256; ++i) {
        const int n = i * 256 + tid;
        vals[i] = memory[(size_t)n * Mc + addrs[i]];
    }
#pragma unroll
    for (int i = 0; i < Nc / 256; ++i) {
        out[(size_t)b * Nc + i * 256 + tid] = vals[i] & 1;
    }
}

extern "C" void kernel_launch(void* const* d_in, const int* in_sizes, int n_in,
                              void* d_out, int out_size, void* d_ws, size_t ws_size,
                              hipStream_t stream) {
    const int* input_bits  = (const int*)d_in[0];  // B*T
    const int* connections = (const int*)d_in[1];  // N*K
    const int* memory      = (const int*)d_in[2];  // N*M
    int* out               = (int*)d_out;          // B*N (bool -> int32)

    if (ws_size >= PACKED_WORDS * sizeof(uint32_t)) {
        uint32_t* packed = (uint32_t*)d_ws;
        // 4M words / 256 threads = 16384 blocks
        hipLaunchKernelGGL(pack_kernel, dim3(PACKED_WORDS / 256), dim3(256), 0, stream,
                           memory, packed);
        hipLaunchKernelGGL(ram_lookup_packed, dim3(Bc), dim3(256), 0, stream,
                           input_bits, connections, packed, out);
    } else {
        hipLaunchKernelGGL(ram_lookup_direct, dim3(Bc), dim3(256), 0, stream,
                           input_bits, connections, memory, out);
    }
}

// Round 4
// 645.680 us; speedup vs baseline: 1.1270x; 1.1270x over previous
//
#include <hip/hip_runtime.h>
#include <cstdint>

// Problem constants (fixed by reference):
#define Bc 1024
#define Tc 4096
#define Nc 2048
#define Kc 16
#define Mc 65536

#define NTILE 16                       // n per gather block (=> 64 B out line per thread)
#define ADDR_BYTES ((size_t)Bc * Nc * sizeof(unsigned short))   // 4 MiB

// ---------------- Pass 1: per-b address computation ----------------
// One block per b. Ballot-pack input row into LDS bitset, compute 16-bit
// addresses for all 2048 n, store coalesced uint16 to addr[(B,N)].
__global__ __launch_bounds__(256) void addr_kernel(
    const int* __restrict__ input_bits,   // (B, T)
    const int* __restrict__ connections,  // (N, K)
    unsigned short* __restrict__ addr)    // (B, N) 16-bit addresses
{
    __shared__ uint32_t bits[Tc / 32];    // 512 B

    const int b    = blockIdx.x;
    const int tid  = threadIdx.x;
    const int lane = tid & 63;
    const int wave = tid >> 6;

    const int* row = input_bits + (size_t)b * Tc;

#pragma unroll
    for (int i = 0; i < Tc / 256; ++i) {
        const int pos = i * 256 + wave * 64 + lane;
        const unsigned long long m = __ballot(row[pos] & 1);
        if (lane == 0) {
            const int w64 = i * 4 + wave;
            bits[w64 * 2]     = (uint32_t)m;
            bits[w64 * 2 + 1] = (uint32_t)(m >> 32);
        }
    }
    __syncthreads();

#pragma unroll
    for (int i = 0; i < Nc / 256; ++i) {
        const int n = i * 256 + tid;
        const int4* cp = (const int4*)(connections + n * Kc);
        const int4 c0 = cp[0], c1 = cp[1], c2 = cp[2], c3 = cp[3];
        const int c[16] = {c0.x, c0.y, c0.z, c0.w,
                           c1.x, c1.y, c1.z, c1.w,
                           c2.x, c2.y, c2.z, c2.w,
                           c3.x, c3.y, c3.z, c3.w};
        uint32_t a = 0;
#pragma unroll
        for (int k = 0; k < 16; ++k) {
            const uint32_t t = (uint32_t)c[k];
            a |= ((bits[t >> 5] >> (t & 31)) & 1u) << k;
        }
        addr[(size_t)b * Nc + n] = (unsigned short)a;   // coalesced 2 B stores
    }
}

// ---------------- Pass 2: per-n-tile gather ----------------
// grid.x = Nc/NTILE (128) n-tiles, grid.y = Bc/256 (4) b-chunks.
// Thread owns one b: 16 addrs (32 B contiguous load), 16 independent gathers
// confined to a 4 MiB window of `memory`, one 64 B coalesced out-line store.
__global__ __launch_bounds__(256) void gather_kernel(
    const unsigned short* __restrict__ addr,  // (B, N)
    const int* __restrict__ memory,           // (N, M)
    int* __restrict__ out)                    // (B, N) bool-as-int32
{
    const int n0 = blockIdx.x * NTILE;
    const int b  = blockIdx.y * 256 + threadIdx.x;

    // Load 16 uint16 addresses = 32 B contiguous.
    const uint32_t* ap = (const uint32_t*)(addr + (size_t)b * Nc + n0);
    uint32_t aw[8];
#pragma unroll
    for (int j = 0; j < 8; ++j) aw[j] = ap[j];

    uint32_t a[NTILE];
#pragma unroll
    for (int j = 0; j < 8; ++j) {
        a[2 * j]     = aw[j] & 0xFFFFu;
        a[2 * j + 1] = aw[j] >> 16;
    }

    // 16 independent gathers, all within memory rows n0..n0+15 (4 MiB window).
    int v[NTILE];
#pragma unroll
    for (int j = 0; j < NTILE; ++j) {
        v[j] = memory[((size_t)(n0 + j) << 16) + a[j]];
    }

    // One full 64 B line per thread, coalesced across the block.
    int4* op = (int4*)(out + (size_t)b * Nc + n0);
#pragma unroll
    for (int j = 0; j < 4; ++j) {
        op[j] = make_int4(v[4 * j] & 1, v[4 * j + 1] & 1,
                          v[4 * j + 2] & 1, v[4 * j + 3] & 1);
    }
}

// ---------------- Fallback: single-pass direct (if ws too small) ----------------
__global__ __launch_bounds__(256) void ram_lookup_direct(
    const int* __restrict__ input_bits,
    const int* __restrict__ connections,
    const int* __restrict__ memory,
    int* __restrict__ out)
{
    __shared__ uint32_t bits[Tc / 32];
    const int b = blockIdx.x, tid = threadIdx.x;
    const int lane = tid & 63, wave = tid >> 6;
    const int* row = input_bits + (size_t)b * Tc;
#pragma unroll
    for (int i = 0; i < Tc / 256; ++i) {
        const int pos = i * 256 + wave * 64 + lane;
        const unsigned long long m = __ballot(row[pos] & 1);
        if (lane == 0) {
            const int w64 = i * 4 + wave;
            bits[w64 * 2] = (uint32_t)m;
            bits[w64 * 2 + 1] = (uint32_t)(m >> 32);
        }
    }
    __syncthreads();
#pragma unroll
    for (int i = 0; i < Nc / 256; ++i) {
        const int n = i * 256 + tid;
        const int4* cp = (const int4*)(connections + n * Kc);
        const int4 c0 = cp[0], c1 = cp[1], c2 = cp[2], c3 = cp[3];
        const int c[16] = {c0.x, c0.y, c0.z, c0.w, c1.x, c1.y, c1.z, c1.w,
                           c2.x, c2.y, c2.z, c2.w, c3.x, c3.y, c3.z, c3.w};
        uint32_t a = 0;
#pragma unroll
        for (int k = 0; k < 16; ++k) {
            const uint32_t t = (uint32_t)c[k];
            a |= ((bits[t >> 5] >> (t & 31)) & 1u) << k;
        }
        out[(size_t)b * Nc + n] = memory[(size_t)n * Mc + a] & 1;
    }
}

extern "C" void kernel_launch(void* const* d_in, const int* in_sizes, int n_in,
                              void* d_out, int out_size, void* d_ws, size_t ws_size,
                              hipStream_t stream) {
    const int* input_bits  = (const int*)d_in[0];  // B*T
    const int* connections = (const int*)d_in[1];  // N*K
    const int* memory      = (const int*)d_in[2];  // N*M
    int* out               = (int*)d_out;          // B*N (bool -> int32)

    if (ws_size >= ADDR_BYTES) {
        unsigned short* addr = (unsigned short*)d_ws;
        hipLaunchKernelGGL(addr_kernel, dim3(Bc), dim3(256), 0, stream,
                           input_bits, connections, addr);
        hipLaunchKernelGGL(gather_kernel, dim3(Nc / NTILE, Bc / 256), dim3(256), 0, stream,
                           addr, memory, out);
    } else {
        hipLaunchKernelGGL(ram_lookup_direct, dim3(Bc), dim3(256), 0, stream,
                           input_bits, connections, memory, out);
    }
}